// Round 3
// baseline (213.510 us; speedup 1.0000x reference)
//
#include <hip/hip_runtime.h>
#include <hip/hip_bf16.h>

#define N_NODES 50000
#define N_EDGES 800000
#define KPTS 15
#define IN_DIM 32
#define OUT_DIM 64
#define KP_EXTENT 0.6f

#define NB 782                     // ceil(50000/64) dst-blocks of 64 nodes
#define NKEY (KPTS * NB)           // 11730 keys = (k, dst_block)
#define NKEY_PAD 12288             // 1024 threads * 12 each for the scan
#define CAP_TOT 11500000           // entry capacity (92 MB of ws; real ~194k)

// ws layout (bytes): cnt @0, off @49152, cursor @98304, entries @147456
#define OFF_OFF    49152
#define CUR_OFF    98304
#define ENT_OFF    147456

// ---------------------------------------------------------------------------
// K1: per-edge geometry -> histogram over (k, dst_block) keys.
// ---------------------------------------------------------------------------
__global__ __launch_bounds__(256) void geom_count(
    const float* __restrict__ pos,
    const float* __restrict__ kp,
    const int*   __restrict__ esrc,
    const int*   __restrict__ edst,
    int*         __restrict__ cnt)
{
    const int e = blockIdx.x * 256 + threadIdx.x;   // grid covers E exactly
    const int s = esrc[e];
    const int d = edst[e];

    const float yx = pos[s * 3 + 0] - pos[d * 3 + 0];
    const float yy = pos[s * 3 + 1] - pos[d * 3 + 1];
    const float yz = pos[s * 3 + 2] - pos[d * 3 + 2];
    const int db = d >> 6;

    #pragma unroll
    for (int k = 0; k < KPTS; ++k) {
        const float dx = yx - kp[k * 3 + 0];
        const float dy = yy - kp[k * 3 + 1];
        const float dz = yz - kp[k * 3 + 2];
        const float dist = sqrtf(dx * dx + dy * dy + dz * dz);
        if (1.0f - dist * (1.0f / KP_EXTENT) > 0.0f)
            atomicAdd(&cnt[k * NB + db], 1);
    }
}

// ---------------------------------------------------------------------------
// K2: single-block exclusive scan over NKEY_PAD counts -> off, cursor.
// ---------------------------------------------------------------------------
__global__ __launch_bounds__(1024) void scan_offsets(
    const int* __restrict__ cnt,
    int*       __restrict__ off,
    int*       __restrict__ cursor)
{
    __shared__ int part[1024];
    const int t = threadIdx.x;

    int v[12];
    int s = 0;
    #pragma unroll
    for (int j = 0; j < 12; ++j) { v[j] = cnt[t * 12 + j]; s += v[j]; }
    part[t] = s;
    __syncthreads();

    // Hillis-Steele inclusive scan over 1024 partials
    for (int d2 = 1; d2 < 1024; d2 <<= 1) {
        const int x = (t >= d2) ? part[t - d2] : 0;
        __syncthreads();
        part[t] += x;
        __syncthreads();
    }

    int base = (t > 0) ? part[t - 1] : 0;
    #pragma unroll
    for (int j = 0; j < 12; ++j) {
        off[t * 12 + j]    = base;
        cursor[t * 12 + j] = base;
        base += v[j];
    }
}

// ---------------------------------------------------------------------------
// K3: per-edge geometry again -> scatter entries grouped by (k, dst_block).
// entry.x = src | (node_local << 16), entry.y = bitcast(m)
// ---------------------------------------------------------------------------
__global__ __launch_bounds__(256) void geom_scatter(
    const float* __restrict__ pos,
    const float* __restrict__ kp,
    const int*   __restrict__ esrc,
    const int*   __restrict__ edst,
    int*         __restrict__ cursor,
    uint2*       __restrict__ entries)
{
    const int e = blockIdx.x * 256 + threadIdx.x;
    const int s = esrc[e];
    const int d = edst[e];

    const float yx = pos[s * 3 + 0] - pos[d * 3 + 0];
    const float yy = pos[s * 3 + 1] - pos[d * 3 + 1];
    const float yz = pos[s * 3 + 2] - pos[d * 3 + 2];
    const int db = d >> 6;
    const unsigned nl = (unsigned)(d & 63);

    #pragma unroll
    for (int k = 0; k < KPTS; ++k) {
        const float dx = yx - kp[k * 3 + 0];
        const float dy = yy - kp[k * 3 + 1];
        const float dz = yz - kp[k * 3 + 2];
        const float dist = sqrtf(dx * dx + dy * dy + dz * dz);
        const float m = 1.0f - dist * (1.0f / KP_EXTENT);
        if (m > 0.0f) {
            const int idx = atomicAdd(&cursor[k * NB + db], 1);
            if (idx < CAP_TOT)
                entries[idx] = make_uint2((unsigned)s | (nl << 16),
                                          __float_as_uint(m));
        }
    }
}

// ---------------------------------------------------------------------------
// K4: one block per 64-node dst-block. LDS-private accumulator, W[k] in
// 32 VGPRs/lane, entries consumed k-major (segment per (k, block)).
// Zero global atomics; single coalesced store of out.
// ---------------------------------------------------------------------------
__global__ __launch_bounds__(256) void gather_mm(
    const float* __restrict__ feat,
    const float* __restrict__ W,        // [15][32][64]
    const int*   __restrict__ cnt,
    const int*   __restrict__ off,
    const uint2* __restrict__ entries,
    float*       __restrict__ out)
{
    __shared__ float sacc[64 * OUT_DIM];   // 16 KB

    const int tid  = threadIdx.x;
    const int lane = tid & 63;
    const int wv   = tid >> 6;             // 0..3
    const int blk  = blockIdx.x;

    for (int i = tid; i < 64 * OUT_DIM; i += 256) sacc[i] = 0.0f;
    __syncthreads();

    for (int k = 0; k < KPTS; ++k) {
        const int key = k * NB + blk;
        const int n   = cnt[key];
        if (n > wv) {
            float w[IN_DIM];
            #pragma unroll
            for (int i = 0; i < IN_DIM; ++i)
                w[i] = W[k * (IN_DIM * OUT_DIM) + i * OUT_DIM + lane];

            const int base = off[key];
            const int end  = min(base + n, CAP_TOT);
            for (int p = base + wv; p < end; p += 4) {
                const uint2 ent = entries[p];      // same addr across wave
                const unsigned sx =
                    (unsigned)__builtin_amdgcn_readfirstlane((int)ent.x);
                const float m = __uint_as_float(
                    __builtin_amdgcn_readfirstlane((int)ent.y));
                const int s  = (int)(sx & 0xffffu);
                const int nl = (int)(sx >> 16);

                const float* __restrict__ f = feat + (s << 5);  // uniform
                float c = 0.0f;
                #pragma unroll
                for (int i = 0; i < IN_DIM; ++i)
                    c = fmaf(f[i], w[i], c);

                atomicAdd(&sacc[nl * OUT_DIM + lane], m * c);   // ds_add_f32
            }
        }
    }
    __syncthreads();

    const int nbase = blk * 64;
    const int nn    = min(64, N_NODES - nbase);
    for (int i = tid; i < nn * OUT_DIM; i += 256)
        out[(size_t)nbase * OUT_DIM + i] = sacc[i];
}

// ---------------------------------------------------------------------------
extern "C" void kernel_launch(void* const* d_in, const int* in_sizes, int n_in,
                              void* d_out, int out_size, void* d_ws, size_t ws_size,
                              hipStream_t stream)
{
    const float* pos  = (const float*)d_in[0];   // [50000,3]
    const float* feat = (const float*)d_in[1];   // [50000,32]
    const float* kp   = (const float*)d_in[2];   // [15,3]
    const float* W    = (const float*)d_in[3];   // [15,32,64]
    const int* esrc   = (const int*)d_in[4];     // [800000]
    const int* edst   = (const int*)d_in[5];     // [800000]
    float* out        = (float*)d_out;           // [50000,64]

    int*   cnt     = (int*)d_ws;
    int*   off     = (int*)((char*)d_ws + OFF_OFF);
    int*   cursor  = (int*)((char*)d_ws + CUR_OFF);
    uint2* entries = (uint2*)((char*)d_ws + ENT_OFF);

    hipMemsetAsync(cnt, 0, NKEY_PAD * sizeof(int), stream);

    const int eblocks = N_EDGES / 256;   // 3125 exactly
    geom_count<<<eblocks, 256, 0, stream>>>(pos, kp, esrc, edst, cnt);
    scan_offsets<<<1, 1024, 0, stream>>>(cnt, off, cursor);
    geom_scatter<<<eblocks, 256, 0, stream>>>(pos, kp, esrc, edst, cursor, entries);
    gather_mm<<<NB, 256, 0, stream>>>(feat, W, cnt, off, entries, out);
}